// Round 12
// baseline (327.694 us; speedup 1.0000x reference)
//
#include <hip/hip_runtime.h>
#include <cstddef>

// Problem constants (from reference)
#define BB   16
#define HHY  128
#define WWX  256
#define CC   64
#define DDp  12
#define HOUT 1024
#define WOUT 2048

typedef _Float16 hf;                                        // storage type
typedef __fp16 h2 __attribute__((ext_vector_type(2)));      // builtin reg pair

__device__ __forceinline__ h2 u2h(unsigned u) { return __builtin_bit_cast(h2, u); }
__device__ __forceinline__ unsigned pkrtz(float a, float b) {
  return __builtin_bit_cast(unsigned, __builtin_amdgcn_cvt_pkrtz(a, b));
}

#if defined(__has_builtin)
#if __has_builtin(__builtin_amdgcn_fdot2)
#define FDOT2(a, b, c) __builtin_amdgcn_fdot2((a), (b), (c), false)
#endif
#endif
#ifndef FDOT2
#define FDOT2(a, b, c) ((float)(a)[0] * (float)(b)[0] + (float)(a)[1] * (float)(b)[1] + (c))
#endif

// |a-b| dot (1,1) accumulated into c (packed fp16 pairs, f32 accum).
__device__ __forceinline__ float adot(unsigned lu, unsigned ru, float c) {
  const h2 d = u2h(lu) - u2h(ru);
  const unsigned au = __builtin_bit_cast(unsigned, d) & 0x7FFF7FFFu;
  return FDOT2(u2h(au), u2h(0x3C003C00u), c);
}

// ---------------------------------------------------------------------------
// prep: convert conv weights to fp16, repacked [tap27][co][ci] so the ci pairs
// consumed by v_dot2_f32_f16 are contiguous. w1,w2,w3: 432 each; wf: 108.
// ---------------------------------------------------------------------------
__global__ __launch_bounds__(256) void prep_k(const float* __restrict__ w1,
                                              const float* __restrict__ w2,
                                              const float* __restrict__ w3,
                                              const float* __restrict__ wf,
                                              hf* __restrict__ o) {
  const int t = threadIdx.x;
  for (int i = t; i < 432; i += 256) {
    const int t27 = i >> 4;
    const int ci = (i >> 2) & 3;
    const int co = i & 3;
    const int dst = (t27 * 4 + co) * 4 + ci;
    o[dst]       = (hf)w1[i];
    o[432 + dst] = (hf)w2[i];
    o[864 + dst] = (hf)w3[i];
  }
  for (int i = t; i < 108; i += 256) o[1296 + i] = (hf)wf[i];  // [t27][ci], COUT=1
}

// ---------------------------------------------------------------------------
// Kernel 1: cost volume (f32 out) — REVERTED to the round-10 version (best
// measured: 102-114us). fp16 single-barrier, k-outer/d-inner, zero-row.
// (r11 DMA variant regressed: 1 block/CU, latency-serial even when L3-warm.)
// ---------------------------------------------------------------------------
#define RSTRIDE 36
#define ZROW WWX

__global__ __launch_bounds__(256) void cost_volume_k(const float* __restrict__ L,
                                                     const float* __restrict__ R,
                                                     float* __restrict__ cost) {
  __shared__ unsigned lsR[(WWX + 1) * RSTRIDE];   // 36 KB + 144 B (row 256 = 0)
  const int t = threadIdx.x;
  const int h = blockIdx.x;
  const int b = blockIdx.y;
  const size_t rowbase = ((size_t)(b * HHY + h)) * WWX;
  const float* Lrow = L + rowbase * CC;
  const float* Rrow = R + rowbase * CC;

  if (t < RSTRIDE) lsR[ZROW * RSTRIDE + t] = 0u;

  // Stage R: coalesced float4 loads (16 lanes/row), convert to fp16 pairs.
#pragma unroll
  for (int j = 0; j < 16; ++j) {
    const int fi = t + 256 * j;        // float4 id in [0,4096)
    const int w = fi >> 4;
    const int f4 = fi & 15;
    const float4 v = *(const float4*)(Rrow + (size_t)w * CC + 4 * f4);
    *(uint2*)(&lsR[w * RSTRIDE + f4 * 2]) =
        make_uint2(pkrtz(v.x, v.y), pkrtz(v.z, v.w));
  }

  // L: thread t owns row t; 16 float4 = 4 full 64B lines, converted to h2.
  unsigned lh[32];
#pragma unroll
  for (int k = 0; k < 16; ++k) {
    const float4 v = *(const float4*)(Lrow + (size_t)t * CC + 4 * k);
    lh[2 * k]     = pkrtz(v.x, v.y);
    lh[2 * k + 1] = pkrtz(v.z, v.w);
  }

  __syncthreads();   // the ONLY barrier

  // Per-d LDS row base; OOB d -> zero row (gives sum|L| = zero-pad value).
  int rb[DDp];
#pragma unroll
  for (int d = 0; d < DDp; ++d) rb[d] = (t >= d ? (t - d) : ZROW) * RSTRIDE;

  float acc[DDp];
#pragma unroll
  for (int d = 0; d < DDp; ++d) acc[d] = 0.f;

#pragma unroll
  for (int k = 0; k < 8; ++k) {
    const unsigned l0 = lh[4 * k], l1 = lh[4 * k + 1],
                   l2 = lh[4 * k + 2], l3 = lh[4 * k + 3];
#pragma unroll
    for (int d = 0; d < DDp; ++d) {
      const uint4 r = *(const uint4*)(&lsR[rb[d] + 4 * k]);
      float a = acc[d];
      a = adot(l0, r.x, a);
      a = adot(l1, r.y, a);
      a = adot(l2, r.z, a);
      a = adot(l3, r.w, a);
      acc[d] = a;
    }
  }

  float* cp = cost + (rowbase + t) * DDp;
#pragma unroll
  for (int d = 0; d < DDp; d += 4)
    *(float4*)(cp + d) = make_float4(acc[d], acc[d + 1], acc[d + 2], acc[d + 3]);
}

// ---------------------------------------------------------------------------
// conv0: 3x3x3, CIN=1 (f32 cost) -> COUT=4 (fp16 out). NO LDS / NO BARRIERS:
// thread (b,h,w) direct-loads its 9 tap-rows (3 float4 each, coalesced across
// lanes, stride 48B) relying on L1/L2/L3 (input 25MB, L3-resident; w-overlap
// L1-hit). w edges: clamped address + cndmask zero. Full occupancy.
// ---------------------------------------------------------------------------
__global__ __launch_bounds__(256) void conv0_k(const float* __restrict__ x,
                                               const float* __restrict__ wt,
                                               const float* __restrict__ bs,
                                               hf* __restrict__ y) {
  const int t = threadIdx.x;
  const int id = blockIdx.x;
  const int h = ((id & 7) << 4) | ((id >> 3) & 15);  // XCD-contiguous h chunks
  const int b = id >> 7;

  float acc[DDp][4];
#pragma unroll
  for (int co = 0; co < 4; ++co) {
    const float bv = bs[co];
#pragma unroll
    for (int d = 0; d < DDp; ++d) acc[d][co] = bv;
  }

#pragma unroll
  for (int kh = 0; kh < 3; ++kh) {
    const int hh = h + kh - 1;
    if (hh < 0 || hh >= HHY) continue;  // block-uniform
    const float* xr = x + ((size_t)(b * HHY + hh) * WWX) * DDp;

#pragma unroll
    for (int kw = 0; kw < 3; ++kw) {
      const int ww = t + kw - 1;
      const bool ok = (ww >= 0) && (ww < WWX);
      const float* xp = xr + (size_t)(ok ? ww : t) * DDp;

      float v[DDp];
#pragma unroll
      for (int k = 0; k < 3; ++k) {
        float4 x4 = *(const float4*)(xp + 4 * k);
        if (!ok) x4 = make_float4(0.f, 0.f, 0.f, 0.f);
        ((float4*)v)[k] = x4;
      }

      const float* wp = wt + (size_t)(kh * 3 + kw) * 12;
      float wr[12];
#pragma unroll
      for (int i = 0; i < 12; ++i) wr[i] = wp[i];

#pragma unroll
      for (int vo = 0; vo < DDp; ++vo)
#pragma unroll
        for (int kd = 0; kd < 3; ++kd) {
          const int d = vo + 1 - kd;
          if (d < 0 || d >= DDp) continue;
#pragma unroll
          for (int co = 0; co < 4; ++co)
            acc[d][co] += v[vo] * wr[kd * 4 + co];
        }
    }
  }

  unsigned ov[DDp * 2];
#pragma unroll
  for (int d = 0; d < DDp; ++d) {
    ov[d * 2]     = pkrtz(fmaxf(acc[d][0], 0.f), fmaxf(acc[d][1], 0.f));
    ov[d * 2 + 1] = pkrtz(fmaxf(acc[d][2], 0.f), fmaxf(acc[d][3], 0.f));
  }
  uint4* yp = (uint4*)(y + ((size_t)(b * HHY + h) * WWX + t) * (DDp * 4));
#pragma unroll
  for (int i = 0; i < 6; ++i) yp[i] = ((uint4*)ov)[i];
}

// ---------------------------------------------------------------------------
// Mid/final conv3d 3x3x3, CIN=4, fp16 activations [B,H,W,D,4], f32 accum via
// v_dot2_f32_f16. NO LDS / NO BARRIERS: thread (b,h,w) direct-loads each
// tap-row (6 x uint4 = 96B, coalesced across lanes) from L1/L2/L3. Weights:
// fp16 repacked [tap][co][ci], wave-uniform scalar loads. Full occupancy;
// global-load latency hidden by TLP (32 waves/CU).
// FUSE_SM: COUT=1 final conv + softmax(-cost) + disparity regression.
// ---------------------------------------------------------------------------
template <int COUT, bool FUSE_SM>
__global__ __launch_bounds__(256) void convh_k(const hf* __restrict__ x,
                                               const hf* __restrict__ wh,
                                               const float* __restrict__ bs,
                                               void* __restrict__ yv) {
  constexpr int DCH = DDp * 4;        // 48 halves per w
  const int t = threadIdx.x;
  const int id = blockIdx.x;
  const int h = ((id & 7) << 4) | ((id >> 3) & 15);
  const int b = id >> 7;

  float acc[DDp][COUT];
#pragma unroll
  for (int co = 0; co < COUT; ++co) {
    const float bv = bs[co];
#pragma unroll
    for (int d = 0; d < DDp; ++d) acc[d][co] = bv;
  }

  const unsigned* whu = (const unsigned*)wh;

#pragma unroll
  for (int kh = 0; kh < 3; ++kh) {
    const int hh = h + kh - 1;
    if (hh < 0 || hh >= HHY) continue;  // block-uniform
    const unsigned* xr = (const unsigned*)(x + (size_t)(b * HHY + hh) * WWX * DCH);

#pragma unroll
    for (int kw = 0; kw < 3; ++kw) {
      const int ww = t + kw - 1;
      const bool ok = (ww >= 0) && (ww < WWX);
      const uint4* xp = (const uint4*)(xr + (size_t)(ok ? ww : t) * 24);

      unsigned xv[24];
#pragma unroll
      for (int i = 0; i < 6; ++i) {
        uint4 u = xp[i];
        if (!ok) u = make_uint4(0u, 0u, 0u, 0u);
        ((uint4*)xv)[i] = u;
      }

      // per-tap fp16 weights, wave-uniform scalar loads
      unsigned w01[3][COUT], w23[3][COUT];
      const int tap3 = (kh * 3 + kw) * 3;
#pragma unroll
      for (int kd = 0; kd < 3; ++kd)
#pragma unroll
        for (int co = 0; co < COUT; ++co) {
          const int u0 = ((tap3 + kd) * COUT + co) * 2;
          w01[kd][co] = whu[u0];
          w23[kd][co] = whu[u0 + 1];
        }

#pragma unroll
      for (int vo = 0; vo < DDp; ++vo) {
        const h2 x01 = u2h(xv[vo * 2]), x23 = u2h(xv[vo * 2 + 1]);
#pragma unroll
        for (int kd = 0; kd < 3; ++kd) {
          const int d = vo + 1 - kd;
          if (d < 0 || d >= DDp) continue;
#pragma unroll
          for (int co = 0; co < COUT; ++co)
            acc[d][co] = FDOT2(x01, u2h(w01[kd][co]),
                         FDOT2(x23, u2h(w23[kd][co]), acc[d][co]));
        }
      }
    }
  }

  if constexpr (FUSE_SM) {
    float* y = (float*)yv;
    float mn = acc[0][0];
#pragma unroll
    for (int d = 1; d < DDp; ++d) mn = fminf(mn, acc[d][0]);
    float s = 0.f, sw = 0.f;
#pragma unroll
    for (int d = 0; d < DDp; ++d) {
      const float e = __expf(mn - acc[d][0]);
      s += e;
      sw += e * (float)d;
    }
    y[(size_t)(b * HHY + h) * WWX + t] = sw / s;
  } else {
    hf* y = (hf*)yv;
    unsigned ov[DDp * 2];
#pragma unroll
    for (int d = 0; d < DDp; ++d) {
      ov[d * 2]     = pkrtz(fmaxf(acc[d][0], 0.f), fmaxf(acc[d][1 % COUT], 0.f));
      ov[d * 2 + 1] = pkrtz(fmaxf(acc[d][2 % COUT], 0.f), fmaxf(acc[d][3 % COUT], 0.f));
    }
    uint4* yp = (uint4*)(y + ((size_t)(b * HHY + h) * WWX + t) * DCH);
#pragma unroll
    for (int i = 0; i < 6; ++i) yp[i] = ((uint4*)ov)[i];
  }
}

// ---------------------------------------------------------------------------
// 8x bilinear upsample, 4 outputs per thread (2 input cols x 2 rows -> 4 loads,
// 1 float4 store). jax half-pixel convention; edge renorm == index clamp.
// ---------------------------------------------------------------------------
__global__ __launch_bounds__(256) void resize4_k(const float* __restrict__ pred,
                                                 float* __restrict__ out) {
  const int idx = blockIdx.x * 256 + threadIdx.x;
  const int xg = idx & 511;
  const int y = (idx >> 9) & 1023;
  const int b = idx >> 19;

  const int parity = xg & 1;
  const int m = xg >> 1;
  const int x0 = m - 1 + parity;
  const int x0c = max(x0, 0);
  const int x1c = min(x0 + 1, WWX - 1);
  const float wx0 = (parity ? 0.0625f : 0.5625f);

  const int py = y & 7;
  const int my = y >> 3;
  const int y0 = my - 1 + (py >= 4 ? 1 : 0);
  const float wy = (py >= 4) ? 0.0625f + (py - 4) * 0.125f : 0.5625f + py * 0.125f;
  const int y0c = max(y0, 0);
  const int y1c = min(y0 + 1, HHY - 1);

  const float* pb = pred + (size_t)b * HHY * WWX;
  const float a = pb[y0c * WWX + x0c];
  const float bv = pb[y0c * WWX + x1c];
  const float c = pb[y1c * WWX + x0c];
  const float d = pb[y1c * WWX + x1c];

  const float top0 = a + (bv - a) * wx0;
  const float bot0 = c + (d - c) * wx0;
  const float dtop = (bv - a) * 0.125f;
  const float dbot = (d - c) * 0.125f;

  float4 o;
  o.x = top0 + wy * (bot0 - top0);
  o.y = (top0 + dtop) + wy * ((bot0 + dbot) - (top0 + dtop));
  o.z = (top0 + 2.f * dtop) + wy * ((bot0 + 2.f * dbot) - (top0 + 2.f * dtop));
  o.w = (top0 + 3.f * dtop) + wy * ((bot0 + 3.f * dbot) - (top0 + 3.f * dtop));

  *(float4*)(out + (size_t)idx * 4) = o;
}

// ---------------------------------------------------------------------------
extern "C" void kernel_launch(void* const* d_in, const int* in_sizes, int n_in,
                              void* d_out, int out_size, void* d_ws, size_t ws_size,
                              hipStream_t stream) {
  const float* feat_l = (const float*)d_in[0];
  const float* feat_r = (const float*)d_in[1];
  const float* w0 = (const float*)d_in[2];
  const float* b0 = (const float*)d_in[3];
  const float* w1 = (const float*)d_in[4];
  const float* b1 = (const float*)d_in[5];
  const float* w2 = (const float*)d_in[6];
  const float* b2 = (const float*)d_in[7];
  const float* w3 = (const float*)d_in[8];
  const float* b3 = (const float*)d_in[9];
  const float* wf = (const float*)d_in[10];
  const float* bf = (const float*)d_in[11];
  float* out = (float*)d_out;

  // ws layout: A,B = fp16 activation ping-pong [B,H,W,D,4] (50.3 MB each);
  // C = f32 cost volume (25.2 MB); P = f32 pred (2.1 MB); Wh = fp16 weights.
  char* ws = (char*)d_ws;
  hf*    A  = (hf*)ws;
  hf*    Bf = (hf*)(ws + 50331648);
  float* C  = (float*)(ws + 100663296);
  float* P  = (float*)(ws + 125829120);
  hf*    Wh = (hf*)(ws + 127926272);

  dim3 blk(256);
  prep_k<<<dim3(1), blk, 0, stream>>>(w1, w2, w3, wf, Wh);
  cost_volume_k<<<dim3(HHY, BB), blk, 0, stream>>>(feat_l, feat_r, C);
  conv0_k<<<dim3(HHY * BB), blk, 0, stream>>>(C, w0, b0, A);
  convh_k<4, false><<<dim3(HHY * BB), blk, 0, stream>>>(A,  Wh,        b1, Bf);
  convh_k<4, false><<<dim3(HHY * BB), blk, 0, stream>>>(Bf, Wh + 432,  b2, A);
  convh_k<4, false><<<dim3(HHY * BB), blk, 0, stream>>>(A,  Wh + 864,  b3, Bf);
  convh_k<1, true ><<<dim3(HHY * BB), blk, 0, stream>>>(Bf, Wh + 1296, bf, P);

  const int ngroups = BB * HOUT * (WOUT / 4);
  resize4_k<<<dim3(ngroups / 256), blk, 0, stream>>>(P, out);
}

// Round 13
// 303.586 us; speedup vs baseline: 1.0794x; 1.0794x over previous
//
#include <hip/hip_runtime.h>
#include <cstddef>

// Problem constants (from reference)
#define BB   16
#define HHY  128
#define WWX  256
#define CC   64
#define DDp  12
#define HOUT 1024
#define WOUT 2048

typedef _Float16 hf;                                        // storage type
typedef __fp16 h2 __attribute__((ext_vector_type(2)));      // builtin reg pair

__device__ __forceinline__ h2 u2h(unsigned u) { return __builtin_bit_cast(h2, u); }
__device__ __forceinline__ unsigned pkrtz(float a, float b) {
  return __builtin_bit_cast(unsigned, __builtin_amdgcn_cvt_pkrtz(a, b));
}

#if defined(__has_builtin)
#if __has_builtin(__builtin_amdgcn_fdot2)
#define FDOT2(a, b, c) __builtin_amdgcn_fdot2((a), (b), (c), false)
#endif
#endif
#ifndef FDOT2
#define FDOT2(a, b, c) ((float)(a)[0] * (float)(b)[0] + (float)(a)[1] * (float)(b)[1] + (c))
#endif

// |a-b| dot (1,1) accumulated into c (packed fp16 pairs, f32 accum).
__device__ __forceinline__ float adot(unsigned lu, unsigned ru, float c) {
  const h2 d = u2h(lu) - u2h(ru);
  const unsigned au = __builtin_bit_cast(unsigned, d) & 0x7FFF7FFFu;
  return FDOT2(u2h(au), u2h(0x3C003C00u), c);
}

// ---------------------------------------------------------------------------
// prep: convert conv weights to fp16, repacked [tap27][co][ci] so the ci pairs
// consumed by v_dot2_f32_f16 are contiguous. w1,w2,w3: 432 each; wf: 108.
// ---------------------------------------------------------------------------
__global__ __launch_bounds__(256) void prep_k(const float* __restrict__ w1,
                                              const float* __restrict__ w2,
                                              const float* __restrict__ w3,
                                              const float* __restrict__ wf,
                                              hf* __restrict__ o) {
  const int t = threadIdx.x;
  for (int i = t; i < 432; i += 256) {
    const int t27 = i >> 4;
    const int ci = (i >> 2) & 3;
    const int co = i & 3;
    const int dst = (t27 * 4 + co) * 4 + ci;
    o[dst]       = (hf)w1[i];
    o[432 + dst] = (hf)w2[i];
    o[864 + dst] = (hf)w3[i];
  }
  for (int i = t; i < 108; i += 256) o[1296 + i] = (hf)wf[i];  // [t27][ci], COUT=1
}

// ---------------------------------------------------------------------------
// Kernel 1: cost volume (f32 out). cost[b,h,w,d] = sum_c |L[b,h,w,c]-R[b,h,w-d,c]|
// (zero-pad shift: w<d contributes sum_c |L|).
// CHANNEL-SPLIT 512-thread blocks (r12 post-mortem: all 256-thread variants
// ~100us with every pipe <30% -> serial per-thread program is the bound).
// Thread (w,cg) owns channels [32cg,32cg+32): staging 8 float4, L regs 16,
// compute 576 VALU -- all halved; occupancy ceiling 32 waves/CU (100%).
// Partial sums combined by ALIASING lsR as [12][256] f32 after a barrier
// (conflict-free scalar writes); cg=0 adds and writes out.
// RSTRIDE=36 dwords (32 data fp16 + 4 pad); zero row at ZROW.
// ---------------------------------------------------------------------------
#define RSTRIDE 36
#define ZROW WWX

__global__ __launch_bounds__(512) void cost_volume_k(const float* __restrict__ L,
                                                     const float* __restrict__ R,
                                                     float* __restrict__ cost) {
  __shared__ unsigned lsR[(WWX + 1) * RSTRIDE];   // 36 KB + 144 B (row 256 = 0)
  const int t = threadIdx.x;          // 0..511
  const int w = t & (WWX - 1);
  const int cg = t >> 8;              // channel group: 0 -> c0..31, 1 -> c32..63
  const int h = blockIdx.x;
  const int b = blockIdx.y;
  const size_t rowbase = ((size_t)(b * HHY + h)) * WWX;
  const float* Lrow = L + rowbase * CC;
  const float* Rrow = R + rowbase * CC;

  if (t < RSTRIDE) lsR[ZROW * RSTRIDE + t] = 0u;

  // Stage R: 8 float4 per thread (coalesced, 16 lanes/row), fp16-pack to LDS.
#pragma unroll
  for (int j = 0; j < 8; ++j) {
    const int fi = t + 512 * j;        // float4 id in [0,4096)
    const int rw = fi >> 4;
    const int f4 = fi & 15;
    const float4 v = *(const float4*)(Rrow + (size_t)rw * CC + 4 * f4);
    *(uint2*)(&lsR[rw * RSTRIDE + f4 * 2]) =
        make_uint2(pkrtz(v.x, v.y), pkrtz(v.z, v.w));
  }

  // L: thread owns channels [32cg,32cg+32) of row w: 8 float4 = 2 full lines.
  unsigned lh[16];
#pragma unroll
  for (int k = 0; k < 8; ++k) {
    const float4 v = *(const float4*)(Lrow + (size_t)w * CC + 32 * cg + 4 * k);
    lh[2 * k]     = pkrtz(v.x, v.y);
    lh[2 * k + 1] = pkrtz(v.z, v.w);
  }

  __syncthreads();

  // Per-d LDS row base (+16 dwords for cg=1); OOB d -> zero row.
  int rb[DDp];
#pragma unroll
  for (int d = 0; d < DDp; ++d)
    rb[d] = (w >= d ? (w - d) : ZROW) * RSTRIDE + 16 * cg;

  float acc[DDp];
#pragma unroll
  for (int d = 0; d < DDp; ++d) acc[d] = 0.f;

#pragma unroll
  for (int k = 0; k < 4; ++k) {        // 4 x 4 uints = 32 channels
    const unsigned l0 = lh[4 * k], l1 = lh[4 * k + 1],
                   l2 = lh[4 * k + 2], l3 = lh[4 * k + 3];
#pragma unroll
    for (int d = 0; d < DDp; ++d) {
      const uint4 r = *(const uint4*)(&lsR[rb[d] + 4 * k]);
      float a = acc[d];
      a = adot(l0, r.x, a);
      a = adot(l1, r.y, a);
      a = adot(l2, r.z, a);
      a = adot(l3, r.w, a);
      acc[d] = a;
    }
  }

  // Combine halves: alias lsR as [12][256] f32 (d-major, conflict-free).
  float* ls2 = (float*)lsR;
  __syncthreads();                      // all R reads done before overwrite
  if (cg == 1) {
#pragma unroll
    for (int d = 0; d < DDp; ++d) ls2[d * WWX + w] = acc[d];
  }
  __syncthreads();
  if (cg == 0) {
    float o[DDp];
#pragma unroll
    for (int d = 0; d < DDp; ++d) o[d] = acc[d] + ls2[d * WWX + w];
    float* cp = cost + (rowbase + w) * DDp;
#pragma unroll
    for (int d = 0; d < DDp; d += 4)
      *(float4*)(cp + d) = make_float4(o[d], o[d + 1], o[d + 2], o[d + 3]);
  }
}

// ---------------------------------------------------------------------------
// conv0: 3x3x3, CIN=1 (f32 cost) -> COUT=4 (fp16 out). Block = one (b,h) row
// (XCD h-remap), thread = w. Row staged f32 in LDS stride 20; weights (108 f)
// wave-uniform global loads; fp16 pack on store. (Round-10 version — best.)
// ---------------------------------------------------------------------------
__global__ __launch_bounds__(256) void conv0_k(const float* __restrict__ x,
                                               const float* __restrict__ wt,
                                               const float* __restrict__ bs,
                                               hf* __restrict__ y) {
  constexpr int S = 20;
  __shared__ float ls[WWX * S];   // 20 KB
  const int t = threadIdx.x;
  const int id = blockIdx.x;
  const int h = ((id & 7) << 4) | ((id >> 3) & 15);  // XCD-contiguous h chunks
  const int b = id >> 7;

  float acc[DDp][4];
#pragma unroll
  for (int co = 0; co < 4; ++co) {
    const float bv = bs[co];
#pragma unroll
    for (int d = 0; d < DDp; ++d) acc[d][co] = bv;
  }

#pragma unroll
  for (int kh = 0; kh < 3; ++kh) {
    const int hh = h + kh - 1;
    if (hh < 0 || hh >= HHY) continue;  // block-uniform

    __syncthreads();
    const float* xr = x + ((size_t)(b * HHY + hh) * WWX) * DDp;
#pragma unroll
    for (int j = 0; j < 3; ++j) {
      const int fi4 = t + 256 * j;     // [0,768)
      const int w_ = fi4 / 3;
      const int k_ = fi4 - w_ * 3;
      *(float4*)(&ls[w_ * S + k_ * 4]) = ((const float4*)xr)[fi4];
    }
    __syncthreads();

#pragma unroll
    for (int kw = 0; kw < 3; ++kw) {
      const int ww = t + kw - 1;
      if (ww < 0 || ww >= WWX) continue;
      const float* lp = &ls[ww * S];

      const float* wp = wt + (size_t)(kh * 3 + kw) * 12;
      float wr[12];
#pragma unroll
      for (int i = 0; i < 12; ++i) wr[i] = wp[i];

      float v[DDp];
#pragma unroll
      for (int k = 0; k < 3; ++k)
        ((float4*)v)[k] = *(const float4*)(lp + 4 * k);
#pragma unroll
      for (int vo = 0; vo < DDp; ++vo)
#pragma unroll
        for (int kd = 0; kd < 3; ++kd) {
          const int d = vo + 1 - kd;
          if (d < 0 || d >= DDp) continue;
#pragma unroll
          for (int co = 0; co < 4; ++co)
            acc[d][co] += v[vo] * wr[kd * 4 + co];
        }
    }
  }

  unsigned ov[DDp * 2];
#pragma unroll
  for (int d = 0; d < DDp; ++d) {
    ov[d * 2]     = pkrtz(fmaxf(acc[d][0], 0.f), fmaxf(acc[d][1], 0.f));
    ov[d * 2 + 1] = pkrtz(fmaxf(acc[d][2], 0.f), fmaxf(acc[d][3], 0.f));
  }
  uint4* yp = (uint4*)(y + ((size_t)(b * HHY + h) * WWX + t) * (DDp * 4));
#pragma unroll
  for (int i = 0; i < 6; ++i) yp[i] = ((uint4*)ov)[i];
}

// ---------------------------------------------------------------------------
// Mid/final conv3d 3x3x3, CIN=4, fp16 activations [B,H,W,D,4], f32 accumulate
// via v_dot2_f32_f16. Block = one (b,h) row (XCD h-remap), thread = w. Rows
// staged fp16 in LDS (26-uint stride; 26.6 KB -> 6 blocks/CU). Weights fp16
// repacked [tap][co][ci], wave-uniform scalar loads. (Round-10 version.)
// FUSE_SM: COUT=1 final conv + softmax(-cost) + disparity regression.
// ---------------------------------------------------------------------------
template <int COUT, bool FUSE_SM>
__global__ __launch_bounds__(256) void convh_k(const hf* __restrict__ x,
                                               const hf* __restrict__ wh,
                                               const float* __restrict__ bs,
                                               void* __restrict__ yv) {
  constexpr int DCH = DDp * 4;        // 48 halves per w
  constexpr int SU  = 26;             // LDS stride per w in uints (52 halves)
  __shared__ unsigned lsu[WWX * SU];  // 26624 B

  const int t = threadIdx.x;
  const int id = blockIdx.x;
  const int h = ((id & 7) << 4) | ((id >> 3) & 15);
  const int b = id >> 7;

  float acc[DDp][COUT];
#pragma unroll
  for (int co = 0; co < COUT; ++co) {
    const float bv = bs[co];
#pragma unroll
    for (int d = 0; d < DDp; ++d) acc[d][co] = bv;
  }

  const unsigned* whu = (const unsigned*)wh;

#pragma unroll
  for (int kh = 0; kh < 3; ++kh) {
    const int hh = h + kh - 1;
    if (hh < 0 || hh >= HHY) continue;  // block-uniform

    __syncthreads();
    const uint4* xr = (const uint4*)(x + (size_t)(b * HHY + hh) * WWX * DCH);
#pragma unroll
    for (int j = 0; j < 6; ++j) {
      const int fi4 = t + 256 * j;     // [0,1536)
      const int w_ = fi4 / 6;
      const int k_ = fi4 - w_ * 6;
      const uint4 v = xr[fi4];
      unsigned* dst = &lsu[w_ * SU + k_ * 4];
      *(uint2*)(dst)     = make_uint2(v.x, v.y);
      *(uint2*)(dst + 2) = make_uint2(v.z, v.w);
    }
    __syncthreads();

#pragma unroll
    for (int kw = 0; kw < 3; ++kw) {
      const int ww = t + kw - 1;
      if (ww < 0 || ww >= WWX) continue;  // divergent only at row edges

      // per-tap fp16 weights, wave-uniform scalar loads
      unsigned w01[3][COUT], w23[3][COUT];
      const int tap3 = (kh * 3 + kw) * 3;
#pragma unroll
      for (int kd = 0; kd < 3; ++kd)
#pragma unroll
        for (int co = 0; co < COUT; ++co) {
          const int u0 = ((tap3 + kd) * COUT + co) * 2;
          w01[kd][co] = whu[u0];
          w23[kd][co] = whu[u0 + 1];
        }

      const unsigned* lp = &lsu[ww * SU];
#pragma unroll
      for (int vo = 0; vo < DDp; ++vo) {
        const uint2 xu = *(const uint2*)(lp + vo * 2);
        const h2 x01 = u2h(xu.x), x23 = u2h(xu.y);
#pragma unroll
        for (int kd = 0; kd < 3; ++kd) {
          const int d = vo + 1 - kd;
          if (d < 0 || d >= DDp) continue;
#pragma unroll
          for (int co = 0; co < COUT; ++co)
            acc[d][co] = FDOT2(x01, u2h(w01[kd][co]),
                         FDOT2(x23, u2h(w23[kd][co]), acc[d][co]));
        }
      }
    }
  }

  if constexpr (FUSE_SM) {
    float* y = (float*)yv;
    float mn = acc[0][0];
#pragma unroll
    for (int d = 1; d < DDp; ++d) mn = fminf(mn, acc[d][0]);
    float s = 0.f, sw = 0.f;
#pragma unroll
    for (int d = 0; d < DDp; ++d) {
      const float e = __expf(mn - acc[d][0]);
      s += e;
      sw += e * (float)d;
    }
    y[(size_t)(b * HHY + h) * WWX + t] = sw / s;
  } else {
    hf* y = (hf*)yv;
    unsigned ov[DDp * 2];
#pragma unroll
    for (int d = 0; d < DDp; ++d) {
      ov[d * 2]     = pkrtz(fmaxf(acc[d][0], 0.f), fmaxf(acc[d][1 % COUT], 0.f));
      ov[d * 2 + 1] = pkrtz(fmaxf(acc[d][2 % COUT], 0.f), fmaxf(acc[d][3 % COUT], 0.f));
    }
    uint4* yp = (uint4*)(y + ((size_t)(b * HHY + h) * WWX + t) * DCH);
#pragma unroll
    for (int i = 0; i < 6; ++i) yp[i] = ((uint4*)ov)[i];
  }
}

// ---------------------------------------------------------------------------
// 8x bilinear upsample, 4 outputs per thread (2 input cols x 2 rows -> 4 loads,
// 1 float4 store). jax half-pixel convention; edge renorm == index clamp.
// ---------------------------------------------------------------------------
__global__ __launch_bounds__(256) void resize4_k(const float* __restrict__ pred,
                                                 float* __restrict__ out) {
  const int idx = blockIdx.x * 256 + threadIdx.x;
  const int xg = idx & 511;
  const int y = (idx >> 9) & 1023;
  const int b = idx >> 19;

  const int parity = xg & 1;
  const int m = xg >> 1;
  const int x0 = m - 1 + parity;
  const int x0c = max(x0, 0);
  const int x1c = min(x0 + 1, WWX - 1);
  const float wx0 = (parity ? 0.0625f : 0.5625f);

  const int py = y & 7;
  const int my = y >> 3;
  const int y0 = my - 1 + (py >= 4 ? 1 : 0);
  const float wy = (py >= 4) ? 0.0625f + (py - 4) * 0.125f : 0.5625f + py * 0.125f;
  const int y0c = max(y0, 0);
  const int y1c = min(y0 + 1, HHY - 1);

  const float* pb = pred + (size_t)b * HHY * WWX;
  const float a = pb[y0c * WWX + x0c];
  const float bv = pb[y0c * WWX + x1c];
  const float c = pb[y1c * WWX + x0c];
  const float d = pb[y1c * WWX + x1c];

  const float top0 = a + (bv - a) * wx0;
  const float bot0 = c + (d - c) * wx0;
  const float dtop = (bv - a) * 0.125f;
  const float dbot = (d - c) * 0.125f;

  float4 o;
  o.x = top0 + wy * (bot0 - top0);
  o.y = (top0 + dtop) + wy * ((bot0 + dbot) - (top0 + dtop));
  o.z = (top0 + 2.f * dtop) + wy * ((bot0 + 2.f * dbot) - (top0 + 2.f * dtop));
  o.w = (top0 + 3.f * dtop) + wy * ((bot0 + 3.f * dbot) - (top0 + 3.f * dtop));

  *(float4*)(out + (size_t)idx * 4) = o;
}

// ---------------------------------------------------------------------------
extern "C" void kernel_launch(void* const* d_in, const int* in_sizes, int n_in,
                              void* d_out, int out_size, void* d_ws, size_t ws_size,
                              hipStream_t stream) {
  const float* feat_l = (const float*)d_in[0];
  const float* feat_r = (const float*)d_in[1];
  const float* w0 = (const float*)d_in[2];
  const float* b0 = (const float*)d_in[3];
  const float* w1 = (const float*)d_in[4];
  const float* b1 = (const float*)d_in[5];
  const float* w2 = (const float*)d_in[6];
  const float* b2 = (const float*)d_in[7];
  const float* w3 = (const float*)d_in[8];
  const float* b3 = (const float*)d_in[9];
  const float* wf = (const float*)d_in[10];
  const float* bf = (const float*)d_in[11];
  float* out = (float*)d_out;

  // ws layout: A,B = fp16 activation ping-pong [B,H,W,D,4] (50.3 MB each);
  // C = f32 cost volume (25.2 MB); P = f32 pred (2.1 MB); Wh = fp16 weights.
  char* ws = (char*)d_ws;
  hf*    A  = (hf*)ws;
  hf*    Bf = (hf*)(ws + 50331648);
  float* C  = (float*)(ws + 100663296);
  float* P  = (float*)(ws + 125829120);
  hf*    Wh = (hf*)(ws + 127926272);

  dim3 blk(256);
  prep_k<<<dim3(1), blk, 0, stream>>>(w1, w2, w3, wf, Wh);
  cost_volume_k<<<dim3(HHY, BB), dim3(512), 0, stream>>>(feat_l, feat_r, C);
  conv0_k<<<dim3(HHY * BB), blk, 0, stream>>>(C, w0, b0, A);
  convh_k<4, false><<<dim3(HHY * BB), blk, 0, stream>>>(A,  Wh,        b1, Bf);
  convh_k<4, false><<<dim3(HHY * BB), blk, 0, stream>>>(Bf, Wh + 432,  b2, A);
  convh_k<4, false><<<dim3(HHY * BB), blk, 0, stream>>>(A,  Wh + 864,  b3, Bf);
  convh_k<1, true ><<<dim3(HHY * BB), blk, 0, stream>>>(Bf, Wh + 1296, bf, P);

  const int ngroups = BB * HOUT * (WOUT / 4);
  resize4_k<<<dim3(ngroups / 256), blk, 0, stream>>>(P, out);
}

// Round 14
// 295.827 us; speedup vs baseline: 1.1077x; 1.0262x over previous
//
#include <hip/hip_runtime.h>
#include <cstddef>

// Problem constants (from reference)
#define BB   16
#define HHY  128
#define WWX  256
#define CC   64
#define DDp  12
#define HOUT 1024
#define WOUT 2048

typedef _Float16 hf;                                        // storage type
typedef __fp16 h2 __attribute__((ext_vector_type(2)));      // builtin reg pair

__device__ __forceinline__ h2 u2h(unsigned u) { return __builtin_bit_cast(h2, u); }
__device__ __forceinline__ unsigned pkrtz(float a, float b) {
  return __builtin_bit_cast(unsigned, __builtin_amdgcn_cvt_pkrtz(a, b));
}

#if defined(__has_builtin)
#if __has_builtin(__builtin_amdgcn_fdot2)
#define FDOT2(a, b, c) __builtin_amdgcn_fdot2((a), (b), (c), false)
#endif
#endif
#ifndef FDOT2
#define FDOT2(a, b, c) ((float)(a)[0] * (float)(b)[0] + (float)(a)[1] * (float)(b)[1] + (c))
#endif

// |a-b| dot (1,1) accumulated into c (packed fp16 pairs, f32 accum).
__device__ __forceinline__ float adot(unsigned lu, unsigned ru, float c) {
  const h2 d = u2h(lu) - u2h(ru);
  const unsigned au = __builtin_bit_cast(unsigned, d) & 0x7FFF7FFFu;
  return FDOT2(u2h(au), u2h(0x3C003C00u), c);
}

// ---------------------------------------------------------------------------
// prep: convert conv weights to fp16, repacked [tap27][co][ci] so the ci pairs
// consumed by v_dot2_f32_f16 are contiguous. w1,w2,w3: 432 each; wf: 108.
// ---------------------------------------------------------------------------
__global__ __launch_bounds__(256) void prep_k(const float* __restrict__ w1,
                                              const float* __restrict__ w2,
                                              const float* __restrict__ w3,
                                              const float* __restrict__ wf,
                                              hf* __restrict__ o) {
  const int t = threadIdx.x;
  for (int i = t; i < 432; i += 256) {
    const int t27 = i >> 4;
    const int ci = (i >> 2) & 3;
    const int co = i & 3;
    const int dst = (t27 * 4 + co) * 4 + ci;
    o[dst]       = (hf)w1[i];
    o[432 + dst] = (hf)w2[i];
    o[864 + dst] = (hf)w3[i];
  }
  for (int i = t; i < 108; i += 256) o[1296 + i] = (hf)wf[i];  // [t27][ci], COUT=1
}

// ---------------------------------------------------------------------------
// Kernel 1: cost volume (f32 out). cost[b,h,w,d] = sum_c |L[b,h,w,c]-R[b,h,w-d,c]|
// (zero-pad shift: w<d contributes sum_c |L|).
// r13 post-mortem: 9 structures, all "one block per (b,h) row, long serial
// program", all ~100-110us. This one shrinks the work unit 4x: block =
// (w-tile 64 x all 12 d), grid 8192 blocks; 256 threads = 64 w x 4 dgroups;
// thread computes 3 outputs (d = dg+4j) over 64 channels. fp16 LDS tile:
// 75 R-rows (11-halo, zero-filled) + 64 L-rows, stride 36 dwords (2-way
// phases, free). 20KB LDS + <=64 VGPR -> 8 blocks/CU = 100% occupancy.
// Output transposed through LDS for coalesced float4 stores.
// ---------------------------------------------------------------------------
#define CVS 36        // LDS row stride (dwords): 32 data + 4 pad
#define CVHALO 11
#define CVWT 64
#define CVROWS (CVWT + CVHALO + CVWT)  // 75 R rows + 64 L rows = 139

__global__ __launch_bounds__(256, 8) void cost_volume_k(const float* __restrict__ L,
                                                        const float* __restrict__ R,
                                                        float* __restrict__ cost) {
  __shared__ unsigned ls[CVROWS * CVS];   // 139*36*4 = 20016 B
  const int t = threadIdx.x;
  const int wb = blockIdx.x * CVWT;
  const int h = blockIdx.y;
  const int b = blockIdx.z;
  const size_t rowbase = ((size_t)(b * HHY + h)) * WWX;
  const float* Lrow = L + rowbase * CC;
  const float* Rrow = R + rowbase * CC;

  // Stage tile: rows 0..74 = R (global w' = wb-11+row, zero if <0);
  //             rows 75..138 = L (global w = wb+row-75). f32 -> fp16 pairs.
#pragma unroll
  for (int j = 0; j < 9; ++j) {
    const int fi = t + 256 * j;          // float4 id in [0, 2224)
    if (fi < CVROWS * 16) {
      const int row = fi >> 4;
      const int f4 = fi & 15;
      float4 v = make_float4(0.f, 0.f, 0.f, 0.f);
      if (row < CVWT + CVHALO) {
        const int gw = wb - CVHALO + row;
        if (gw >= 0) v = *(const float4*)(Rrow + (size_t)gw * CC + 4 * f4);
      } else {
        const int gw = wb + row - (CVWT + CVHALO);
        v = *(const float4*)(Lrow + (size_t)gw * CC + 4 * f4);
      }
      *(uint2*)(&ls[row * CVS + f4 * 2]) =
          make_uint2(pkrtz(v.x, v.y), pkrtz(v.z, v.w));
    }
  }
  __syncthreads();

  const int w = t & 63;
  const int dg = t >> 6;                 // wave-uniform
  // R row for d = dg+4j: rw = w + 11 - d  (halo rows <0 already zeroed)
  const int rb0 = (w + CVHALO - dg) * CVS;
  const int rb1 = (w + CVHALO - dg - 4) * CVS;
  const int rb2 = (w + CVHALO - dg - 8) * CVS;
  const int rbL = (CVWT + CVHALO + w) * CVS;

  float a0 = 0.f, a1 = 0.f, a2 = 0.f;
#pragma unroll
  for (int k = 0; k < 8; ++k) {
    const uint4 lq = *(const uint4*)(&ls[rbL + 4 * k]);
    const uint4 r0 = *(const uint4*)(&ls[rb0 + 4 * k]);
    a0 = adot(lq.x, r0.x, a0); a0 = adot(lq.y, r0.y, a0);
    a0 = adot(lq.z, r0.z, a0); a0 = adot(lq.w, r0.w, a0);
    const uint4 r1 = *(const uint4*)(&ls[rb1 + 4 * k]);
    a1 = adot(lq.x, r1.x, a1); a1 = adot(lq.y, r1.y, a1);
    a1 = adot(lq.z, r1.z, a1); a1 = adot(lq.w, r1.w, a1);
    const uint4 r2 = *(const uint4*)(&ls[rb2 + 4 * k]);
    a2 = adot(lq.x, r2.x, a2); a2 = adot(lq.y, r2.y, a2);
    a2 = adot(lq.z, r2.z, a2); a2 = adot(lq.w, r2.w, a2);
  }

  // Transpose through LDS for coalesced output stores.
  __syncthreads();                       // tile reads done before overwrite
  float* lo = (float*)ls;
  lo[w * DDp + dg]     = a0;
  lo[w * DDp + dg + 4] = a1;
  lo[w * DDp + dg + 8] = a2;
  __syncthreads();
  if (t < CVWT * DDp / 4) {              // 192 float4
    const float4 v = *(const float4*)(&lo[4 * t]);
    *(float4*)(cost + (rowbase + wb) * DDp + 4 * t) = v;
  }
}

// ---------------------------------------------------------------------------
// conv0: 3x3x3, CIN=1 (f32 cost) -> COUT=4 (fp16 out). Block = one (b,h) row
// (XCD h-remap), thread = w. Row staged f32 in LDS stride 20; weights (108 f)
// wave-uniform global loads; fp16 pack on store. (Round-10 version — best.)
// ---------------------------------------------------------------------------
__global__ __launch_bounds__(256) void conv0_k(const float* __restrict__ x,
                                               const float* __restrict__ wt,
                                               const float* __restrict__ bs,
                                               hf* __restrict__ y) {
  constexpr int S = 20;
  __shared__ float ls[WWX * S];   // 20 KB
  const int t = threadIdx.x;
  const int id = blockIdx.x;
  const int h = ((id & 7) << 4) | ((id >> 3) & 15);  // XCD-contiguous h chunks
  const int b = id >> 7;

  float acc[DDp][4];
#pragma unroll
  for (int co = 0; co < 4; ++co) {
    const float bv = bs[co];
#pragma unroll
    for (int d = 0; d < DDp; ++d) acc[d][co] = bv;
  }

#pragma unroll
  for (int kh = 0; kh < 3; ++kh) {
    const int hh = h + kh - 1;
    if (hh < 0 || hh >= HHY) continue;  // block-uniform

    __syncthreads();
    const float* xr = x + ((size_t)(b * HHY + hh) * WWX) * DDp;
#pragma unroll
    for (int j = 0; j < 3; ++j) {
      const int fi4 = t + 256 * j;     // [0,768)
      const int w_ = fi4 / 3;
      const int k_ = fi4 - w_ * 3;
      *(float4*)(&ls[w_ * S + k_ * 4]) = ((const float4*)xr)[fi4];
    }
    __syncthreads();

#pragma unroll
    for (int kw = 0; kw < 3; ++kw) {
      const int ww = t + kw - 1;
      if (ww < 0 || ww >= WWX) continue;
      const float* lp = &ls[ww * S];

      const float* wp = wt + (size_t)(kh * 3 + kw) * 12;
      float wr[12];
#pragma unroll
      for (int i = 0; i < 12; ++i) wr[i] = wp[i];

      float v[DDp];
#pragma unroll
      for (int k = 0; k < 3; ++k)
        ((float4*)v)[k] = *(const float4*)(lp + 4 * k);
#pragma unroll
      for (int vo = 0; vo < DDp; ++vo)
#pragma unroll
        for (int kd = 0; kd < 3; ++kd) {
          const int d = vo + 1 - kd;
          if (d < 0 || d >= DDp) continue;
#pragma unroll
          for (int co = 0; co < 4; ++co)
            acc[d][co] += v[vo] * wr[kd * 4 + co];
        }
    }
  }

  unsigned ov[DDp * 2];
#pragma unroll
  for (int d = 0; d < DDp; ++d) {
    ov[d * 2]     = pkrtz(fmaxf(acc[d][0], 0.f), fmaxf(acc[d][1], 0.f));
    ov[d * 2 + 1] = pkrtz(fmaxf(acc[d][2], 0.f), fmaxf(acc[d][3], 0.f));
  }
  uint4* yp = (uint4*)(y + ((size_t)(b * HHY + h) * WWX + t) * (DDp * 4));
#pragma unroll
  for (int i = 0; i < 6; ++i) yp[i] = ((uint4*)ov)[i];
}

// ---------------------------------------------------------------------------
// Mid/final conv3d 3x3x3, CIN=4, fp16 activations [B,H,W,D,4], f32 accumulate
// via v_dot2_f32_f16. Block = one (b,h) row (XCD h-remap), thread = w. Rows
// staged fp16 in LDS (26-uint stride; 26.6 KB -> 6 blocks/CU). Weights fp16
// repacked [tap][co][ci], wave-uniform scalar loads. (Round-10 version.)
// FUSE_SM: COUT=1 final conv + softmax(-cost) + disparity regression.
// ---------------------------------------------------------------------------
template <int COUT, bool FUSE_SM>
__global__ __launch_bounds__(256) void convh_k(const hf* __restrict__ x,
                                               const hf* __restrict__ wh,
                                               const float* __restrict__ bs,
                                               void* __restrict__ yv) {
  constexpr int DCH = DDp * 4;        // 48 halves per w
  constexpr int SU  = 26;             // LDS stride per w in uints (52 halves)
  __shared__ unsigned lsu[WWX * SU];  // 26624 B

  const int t = threadIdx.x;
  const int id = blockIdx.x;
  const int h = ((id & 7) << 4) | ((id >> 3) & 15);
  const int b = id >> 7;

  float acc[DDp][COUT];
#pragma unroll
  for (int co = 0; co < COUT; ++co) {
    const float bv = bs[co];
#pragma unroll
    for (int d = 0; d < DDp; ++d) acc[d][co] = bv;
  }

  const unsigned* whu = (const unsigned*)wh;

#pragma unroll
  for (int kh = 0; kh < 3; ++kh) {
    const int hh = h + kh - 1;
    if (hh < 0 || hh >= HHY) continue;  // block-uniform

    __syncthreads();
    const uint4* xr = (const uint4*)(x + (size_t)(b * HHY + hh) * WWX * DCH);
#pragma unroll
    for (int j = 0; j < 6; ++j) {
      const int fi4 = t + 256 * j;     // [0,1536)
      const int w_ = fi4 / 6;
      const int k_ = fi4 - w_ * 6;
      const uint4 v = xr[fi4];
      unsigned* dst = &lsu[w_ * SU + k_ * 4];
      *(uint2*)(dst)     = make_uint2(v.x, v.y);
      *(uint2*)(dst + 2) = make_uint2(v.z, v.w);
    }
    __syncthreads();

#pragma unroll
    for (int kw = 0; kw < 3; ++kw) {
      const int ww = t + kw - 1;
      if (ww < 0 || ww >= WWX) continue;  // divergent only at row edges

      // per-tap fp16 weights, wave-uniform scalar loads
      unsigned w01[3][COUT], w23[3][COUT];
      const int tap3 = (kh * 3 + kw) * 3;
#pragma unroll
      for (int kd = 0; kd < 3; ++kd)
#pragma unroll
        for (int co = 0; co < COUT; ++co) {
          const int u0 = ((tap3 + kd) * COUT + co) * 2;
          w01[kd][co] = whu[u0];
          w23[kd][co] = whu[u0 + 1];
        }

      const unsigned* lp = &lsu[ww * SU];
#pragma unroll
      for (int vo = 0; vo < DDp; ++vo) {
        const uint2 xu = *(const uint2*)(lp + vo * 2);
        const h2 x01 = u2h(xu.x), x23 = u2h(xu.y);
#pragma unroll
        for (int kd = 0; kd < 3; ++kd) {
          const int d = vo + 1 - kd;
          if (d < 0 || d >= DDp) continue;
#pragma unroll
          for (int co = 0; co < COUT; ++co)
            acc[d][co] = FDOT2(x01, u2h(w01[kd][co]),
                         FDOT2(x23, u2h(w23[kd][co]), acc[d][co]));
        }
      }
    }
  }

  if constexpr (FUSE_SM) {
    float* y = (float*)yv;
    float mn = acc[0][0];
#pragma unroll
    for (int d = 1; d < DDp; ++d) mn = fminf(mn, acc[d][0]);
    float s = 0.f, sw = 0.f;
#pragma unroll
    for (int d = 0; d < DDp; ++d) {
      const float e = __expf(mn - acc[d][0]);
      s += e;
      sw += e * (float)d;
    }
    y[(size_t)(b * HHY + h) * WWX + t] = sw / s;
  } else {
    hf* y = (hf*)yv;
    unsigned ov[DDp * 2];
#pragma unroll
    for (int d = 0; d < DDp; ++d) {
      ov[d * 2]     = pkrtz(fmaxf(acc[d][0], 0.f), fmaxf(acc[d][1 % COUT], 0.f));
      ov[d * 2 + 1] = pkrtz(fmaxf(acc[d][2 % COUT], 0.f), fmaxf(acc[d][3 % COUT], 0.f));
    }
    uint4* yp = (uint4*)(y + ((size_t)(b * HHY + h) * WWX + t) * DCH);
#pragma unroll
    for (int i = 0; i < 6; ++i) yp[i] = ((uint4*)ov)[i];
  }
}

// ---------------------------------------------------------------------------
// 8x bilinear upsample, 4 outputs per thread (2 input cols x 2 rows -> 4 loads,
// 1 float4 store). jax half-pixel convention; edge renorm == index clamp.
// ---------------------------------------------------------------------------
__global__ __launch_bounds__(256) void resize4_k(const float* __restrict__ pred,
                                                 float* __restrict__ out) {
  const int idx = blockIdx.x * 256 + threadIdx.x;
  const int xg = idx & 511;
  const int y = (idx >> 9) & 1023;
  const int b = idx >> 19;

  const int parity = xg & 1;
  const int m = xg >> 1;
  const int x0 = m - 1 + parity;
  const int x0c = max(x0, 0);
  const int x1c = min(x0 + 1, WWX - 1);
  const float wx0 = (parity ? 0.0625f : 0.5625f);

  const int py = y & 7;
  const int my = y >> 3;
  const int y0 = my - 1 + (py >= 4 ? 1 : 0);
  const float wy = (py >= 4) ? 0.0625f + (py - 4) * 0.125f : 0.5625f + py * 0.125f;
  const int y0c = max(y0, 0);
  const int y1c = min(y0 + 1, HHY - 1);

  const float* pb = pred + (size_t)b * HHY * WWX;
  const float a = pb[y0c * WWX + x0c];
  const float bv = pb[y0c * WWX + x1c];
  const float c = pb[y1c * WWX + x0c];
  const float d = pb[y1c * WWX + x1c];

  const float top0 = a + (bv - a) * wx0;
  const float bot0 = c + (d - c) * wx0;
  const float dtop = (bv - a) * 0.125f;
  const float dbot = (d - c) * 0.125f;

  float4 o;
  o.x = top0 + wy * (bot0 - top0);
  o.y = (top0 + dtop) + wy * ((bot0 + dbot) - (top0 + dtop));
  o.z = (top0 + 2.f * dtop) + wy * ((bot0 + 2.f * dbot) - (top0 + 2.f * dtop));
  o.w = (top0 + 3.f * dtop) + wy * ((bot0 + 3.f * dbot) - (top0 + 3.f * dtop));

  *(float4*)(out + (size_t)idx * 4) = o;
}

// ---------------------------------------------------------------------------
extern "C" void kernel_launch(void* const* d_in, const int* in_sizes, int n_in,
                              void* d_out, int out_size, void* d_ws, size_t ws_size,
                              hipStream_t stream) {
  const float* feat_l = (const float*)d_in[0];
  const float* feat_r = (const float*)d_in[1];
  const float* w0 = (const float*)d_in[2];
  const float* b0 = (const float*)d_in[3];
  const float* w1 = (const float*)d_in[4];
  const float* b1 = (const float*)d_in[5];
  const float* w2 = (const float*)d_in[6];
  const float* b2 = (const float*)d_in[7];
  const float* w3 = (const float*)d_in[8];
  const float* b3 = (const float*)d_in[9];
  const float* wf = (const float*)d_in[10];
  const float* bf = (const float*)d_in[11];
  float* out = (float*)d_out;

  // ws layout: A,B = fp16 activation ping-pong [B,H,W,D,4] (50.3 MB each);
  // C = f32 cost volume (25.2 MB); P = f32 pred (2.1 MB); Wh = fp16 weights.
  char* ws = (char*)d_ws;
  hf*    A  = (hf*)ws;
  hf*    Bf = (hf*)(ws + 50331648);
  float* C  = (float*)(ws + 100663296);
  float* P  = (float*)(ws + 125829120);
  hf*    Wh = (hf*)(ws + 127926272);

  dim3 blk(256);
  prep_k<<<dim3(1), blk, 0, stream>>>(w1, w2, w3, wf, Wh);
  cost_volume_k<<<dim3(WWX / CVWT, HHY, BB), blk, 0, stream>>>(feat_l, feat_r, C);
  conv0_k<<<dim3(HHY * BB), blk, 0, stream>>>(C, w0, b0, A);
  convh_k<4, false><<<dim3(HHY * BB), blk, 0, stream>>>(A,  Wh,        b1, Bf);
  convh_k<4, false><<<dim3(HHY * BB), blk, 0, stream>>>(Bf, Wh + 432,  b2, A);
  convh_k<4, false><<<dim3(HHY * BB), blk, 0, stream>>>(A,  Wh + 864,  b3, Bf);
  convh_k<1, true ><<<dim3(HHY * BB), blk, 0, stream>>>(Bf, Wh + 1296, bf, P);

  const int ngroups = BB * HOUT * (WOUT / 4);
  resize4_k<<<dim3(ngroups / 256), blk, 0, stream>>>(P, out);
}